// Round 1
// baseline (1711.936 us; speedup 1.0000x reference)
//
#include <hip/hip_runtime.h>
#include <hip/hip_bf16.h>

#define N_NODESC 50000
#define N_EDGESC 400000
#define N_GRAPHSC 250
#define DDIM 256
#define NCLS 10
#define BN_EPSF 1e-5f

// ---------------- CSR build ----------------

__global__ void k_zero32(int* __restrict__ p, int n) {
    int i = blockIdx.x * blockDim.x + threadIdx.x;
    if (i < n) p[i] = 0;
}

__global__ void k_count(const int* __restrict__ dst, int* __restrict__ cnt) {
    int e = blockIdx.x * blockDim.x + threadIdx.x;
    if (e < N_EDGESC) atomicAdd(&cnt[dst[e]], 1);
}

__global__ __launch_bounds__(1024) void k_scan(const int* __restrict__ deg,
                                               int* __restrict__ rowstart) {
    __shared__ int ps[1024];
    int tid = threadIdx.x;
    const int CH = (N_NODESC + 1023) / 1024;  // 49
    int beg = tid * CH;
    int end = min(beg + CH, N_NODESC);
    int s = 0;
    for (int i = beg; i < end; i++) s += deg[i];
    ps[tid] = s;
    __syncthreads();
    for (int off = 1; off < 1024; off <<= 1) {
        int v = (tid >= off) ? ps[tid - off] : 0;
        __syncthreads();
        ps[tid] += v;
        __syncthreads();
    }
    int run = (tid == 0) ? 0 : ps[tid - 1];
    for (int i = beg; i < end; i++) { rowstart[i] = run; run += deg[i]; }
    if (tid == 1023) rowstart[N_NODESC] = ps[1023];
}

__global__ void k_fill(const int* __restrict__ src, const int* __restrict__ dst,
                       const int* __restrict__ rowstart, int* __restrict__ cur,
                       int* __restrict__ esrc) {
    int e = blockIdx.x * blockDim.x + threadIdx.x;
    if (e < N_EDGESC) {
        int d = dst[e];
        int pos = rowstart[d] + atomicAdd(&cur[d], 1);
        esrc[pos] = src[e];
    }
}

// ---------------- mean aggregation:  H = X + mean_{in-edges}(X[src]) ----------------
// one 64-lane wave per node, lane handles 4 consecutive features (float4)

__global__ __launch_bounds__(256) void k_agg(const float* __restrict__ X,
                                             const int* __restrict__ esrc,
                                             const int* __restrict__ rowstart,
                                             float* __restrict__ Hout) {
    int node = blockIdx.x * 4 + (threadIdx.x >> 6);
    if (node >= N_NODESC) return;
    int lane = threadIdx.x & 63;
    int beg = rowstart[node];
    int end = rowstart[node + 1];
    float4 s = make_float4(0.f, 0.f, 0.f, 0.f);
    for (int j = beg; j < end; j++) {
        int sn = esrc[j];
        float4 v = *(const float4*)(X + (size_t)sn * DDIM + lane * 4);
        s.x += v.x; s.y += v.y; s.z += v.z; s.w += v.w;
    }
    int deg = end - beg;
    float inv = (deg > 0) ? 1.0f / (float)deg : 0.0f;
    float4 xv = *(const float4*)(X + (size_t)node * DDIM + lane * 4);
    float4 o;
    o.x = xv.x + s.x * inv;
    o.y = xv.y + s.y * inv;
    o.z = xv.z + s.z * inv;
    o.w = xv.w + s.w * inv;
    *(float4*)(Hout + (size_t)node * DDIM + lane * 4) = o;
}

// ---------------- fp32 GEMM:  C = relu(A @ W + bias),  A[M][256], W[256][256] ----------------
// 64x64 tile, BK=16, 256 threads, 4x4 micro-tile per thread

__global__ __launch_bounds__(256) void k_gemm(const float* __restrict__ A,
                                              const float* __restrict__ W,
                                              const float* __restrict__ bias,
                                              float* __restrict__ C, int M) {
    __shared__ float As[16][64];  // [k][m]
    __shared__ float Bs[16][64];  // [k][n]
    int tid = threadIdx.x;
    int bm = blockIdx.x;
    int bn = blockIdx.y;
    int tx = tid & 15;   // n-dir
    int ty = tid >> 4;   // m-dir
    float acc[4][4] = {{0.f}};

    const float* Wblk = W + bn * 64;

    for (int k0 = 0; k0 < 256; k0 += 16) {
        // A tile: 64 rows x 16 cols, one float4 per thread
        {
            int r = tid >> 2;
            int c4 = (tid & 3) * 4;
            int gr = bm * 64 + r;
            float4 v = make_float4(0.f, 0.f, 0.f, 0.f);
            if (gr < M) v = *(const float4*)(A + (size_t)gr * 256 + k0 + c4);
            As[c4 + 0][r] = v.x;
            As[c4 + 1][r] = v.y;
            As[c4 + 2][r] = v.z;
            As[c4 + 3][r] = v.w;
            // W tile: 16 rows x 64 cols, one float4 per thread
            int wr = tid >> 4;
            int wc = (tid & 15) * 4;
            float4 wv = *(const float4*)(Wblk + (size_t)(k0 + wr) * 256 + wc);
            *(float4*)&Bs[wr][wc] = wv;
        }
        __syncthreads();
#pragma unroll
        for (int k = 0; k < 16; k++) {
            float a[4], b[4];
            *(float4*)a = *(const float4*)&As[k][ty * 4];
            *(float4*)b = *(const float4*)&Bs[k][tx * 4];
#pragma unroll
            for (int i = 0; i < 4; i++)
#pragma unroll
                for (int j = 0; j < 4; j++) acc[i][j] += a[i] * b[j];
        }
        __syncthreads();
    }

    float4 bb = *(const float4*)(bias + bn * 64 + tx * 4);
#pragma unroll
    for (int i = 0; i < 4; i++) {
        int row = bm * 64 + ty * 4 + i;
        if (row < M) {
            float4 o;
            o.x = fmaxf(acc[i][0] + bb.x, 0.f);
            o.y = fmaxf(acc[i][1] + bb.y, 0.f);
            o.z = fmaxf(acc[i][2] + bb.z, 0.f);
            o.w = fmaxf(acc[i][3] + bb.w, 0.f);
            *(float4*)(C + (size_t)row * 256 + bn * 64 + tx * 4) = o;
        }
    }
}

// ---------------- BN statistics + normalize ----------------

__global__ __launch_bounds__(256) void k_colreduce(const float* __restrict__ H,
                                                   float* __restrict__ cs,
                                                   float* __restrict__ css, int M) {
    int d = threadIdx.x;  // 256 features
    float s = 0.f, ss = 0.f;
    for (int n = blockIdx.x; n < M; n += gridDim.x) {
        float v = H[(size_t)n * DDIM + d];
        s += v;
        ss += v * v;
    }
    atomicAdd(&cs[d], s);
    atomicAdd(&css[d], ss);
}

__global__ __launch_bounds__(256) void k_bn(const float* __restrict__ H,
                                            const float* __restrict__ cs,
                                            const float* __restrict__ css,
                                            const float* __restrict__ gamma,
                                            const float* __restrict__ beta,
                                            float* __restrict__ Y, int M) {
    const float invN = 1.0f / (float)M;
    int total = M * (DDIM / 4);
    for (int i = blockIdx.x * blockDim.x + threadIdx.x; i < total;
         i += gridDim.x * blockDim.x) {
        int d4 = (i & 63) * 4;
        float4 h = ((const float4*)H)[i];
        float4 o;
#pragma unroll
        for (int j = 0; j < 4; j++) {
            int d = d4 + j;
            float mu = cs[d] * invN;
            float var = css[d] * invN - mu * mu;
            float sc = gamma[d] * rsqrtf(var + BN_EPSF);
            float hv = (&h.x)[j];
            (&o.x)[j] = sc * (hv - mu) + beta[d];
        }
        ((float4*)Y)[i] = o;
    }
}

// ---------------- classification head ----------------

__global__ __launch_bounds__(256) void k_head(const float* __restrict__ Y,
                                              const int* __restrict__ counts,
                                              const float* __restrict__ fcW1,
                                              const float* __restrict__ fcb1,
                                              const float* __restrict__ fcW2,
                                              const float* __restrict__ fcb2,
                                              float* __restrict__ out) {
    int g = blockIdx.x;
    __shared__ float row[DDIM];
    __shared__ float gv[DDIM];
    __shared__ float logits[NCLS];
    __shared__ int lastIdx;
    if (threadIdx.x == 0) {
        int s = 0;
        for (int i = 0; i <= g; i++) s += counts[i];
        lastIdx = s - 1;
    }
    __syncthreads();
    int j = threadIdx.x;
    row[j] = Y[(size_t)lastIdx * DDIM + j];
    __syncthreads();
    float acc = fcb1[j];
    for (int d = 0; d < DDIM; d++) acc += row[d] * fcW1[(size_t)d * DDIM + j];
    gv[j] = fmaxf(acc, 0.f);
    __syncthreads();
    if (j < NCLS) {
        float a = fcb2[j];
        for (int d = 0; d < DDIM; d++) a += gv[d] * fcW2[(size_t)d * NCLS + j];
        logits[j] = a;
    }
    __syncthreads();
    if (j == 0) {
        float m = -1e30f;
        for (int c = 0; c < NCLS; c++) m = fmaxf(m, logits[c]);
        float se = 0.f;
        for (int c = 0; c < NCLS; c++) se += expf(logits[c] - m);
        float lse = m + logf(se);
        for (int c = 0; c < NCLS; c++) out[g * NCLS + c] = logits[c] - lse;
    }
}

// ---------------- launcher ----------------

extern "C" void kernel_launch(void* const* d_in, const int* in_sizes, int n_in,
                              void* d_out, int out_size, void* d_ws, size_t ws_size,
                              hipStream_t stream) {
    const float* x    = (const float*)d_in[0];
    const int* src    = (const int*)d_in[1];
    const int* dst    = (const int*)d_in[2];
    const int* counts = (const int*)d_in[3];
    const float* W1a  = (const float*)d_in[4];
    const float* b1a  = (const float*)d_in[5];
    const float* W1b  = (const float*)d_in[6];
    const float* b1b  = (const float*)d_in[7];
    const float* g1   = (const float*)d_in[8];
    const float* be1  = (const float*)d_in[9];
    const float* Ws1  = (const float*)d_in[10];
    const float* bs1  = (const float*)d_in[11];
    const float* Ws2  = (const float*)d_in[12];
    const float* bs2  = (const float*)d_in[13];
    const float* gms  = (const float*)d_in[14];
    const float* bts  = (const float*)d_in[15];
    const float* fcW1 = (const float*)d_in[16];
    const float* fcb1 = (const float*)d_in[17];
    const float* fcW2 = (const float*)d_in[18];
    const float* fcb2 = (const float*)d_in[19];
    float* out = (float*)d_out;

    char* ws = (char*)d_ws;
    float* H0      = (float*)(ws);                 // 51,200,000 B
    float* H1      = (float*)(ws + 51200000);      // 51,200,000 B
    int* rowstart  = (int*)(ws + 102400000);       // 200,004 B
    int* cursor    = (int*)(ws + 102600192);       // 200,000 B
    int* esrc      = (int*)(ws + 102800384);       // 1,600,000 B
    float* colsum  = (float*)(ws + 104400384);     // 256 + 256 f32 (sum, sumsq)

    // ---- CSR build (once per call) ----
    k_zero32<<<dim3((N_NODESC + 255) / 256), 256, 0, stream>>>(cursor, N_NODESC);
    k_count<<<dim3((N_EDGESC + 255) / 256), 256, 0, stream>>>(dst, cursor);
    k_scan<<<1, 1024, 0, stream>>>(cursor, rowstart);
    k_zero32<<<dim3((N_NODESC + 255) / 256), 256, 0, stream>>>(cursor, N_NODESC);
    k_fill<<<dim3((N_EDGESC + 255) / 256), 256, 0, stream>>>(src, dst, rowstart,
                                                             cursor, esrc);

    // ---- 5 GIN layers ----
    for (int l = 0; l < 5; ++l) {
        const float* X  = (l == 0) ? x : H1;
        const float* W1 = (l == 0) ? W1a : Ws1 + (size_t)(l - 1) * 65536;
        const float* B1 = (l == 0) ? b1a : bs1 + (l - 1) * 256;
        const float* W2 = (l == 0) ? W1b : Ws2 + (size_t)(l - 1) * 65536;
        const float* B2 = (l == 0) ? b1b : bs2 + (l - 1) * 256;
        const float* GA = (l == 0) ? g1 : gms + (l - 1) * 256;
        const float* BE = (l == 0) ? be1 : bts + (l - 1) * 256;

        k_agg<<<dim3(12500), 256, 0, stream>>>(X, esrc, rowstart, H0);
        k_gemm<<<dim3(782, 4), 256, 0, stream>>>(H0, W1, B1, H1, N_NODESC);
        k_zero32<<<1, 512, 0, stream>>>((int*)colsum, 512);
        k_gemm<<<dim3(782, 4), 256, 0, stream>>>(H1, W2, B2, H0, N_NODESC);
        k_colreduce<<<dim3(512), 256, 0, stream>>>(H0, colsum, colsum + 256,
                                                   N_NODESC);
        k_bn<<<dim3(2048), 256, 0, stream>>>(H0, colsum, colsum + 256, GA, BE, H1,
                                             N_NODESC);
    }

    // ---- head ----
    k_head<<<dim3(N_GRAPHSC), 256, 0, stream>>>(H1, counts, fcW1, fcb1, fcW2, fcb2,
                                                out);
}

// Round 3
// 883.862 us; speedup vs baseline: 1.9369x; 1.9369x over previous
//
#include <hip/hip_runtime.h>
#include <hip/hip_bf16.h>

#define N_NODESC 50000
#define N_EDGESC 400000
#define N_GRAPHSC 250
#define DDIM 256
#define NCLS 10
#define BN_EPSF 1e-5f
#define MPAD 50048   // 391 * 128

typedef __attribute__((ext_vector_type(4))) float f32x4;
typedef __attribute__((ext_vector_type(8))) short bf16x8;
typedef __attribute__((ext_vector_type(8))) unsigned short u16x8;

__device__ __forceinline__ float bf2f(unsigned short h) {
    union { unsigned int u; float f; } c;
    c.u = ((unsigned int)h) << 16;
    return c.f;
}
__device__ __forceinline__ unsigned short f2bf(float f) {
    union { float f; unsigned int u; } c;
    c.f = f;
    unsigned int u = c.u;
    return (unsigned short)((u + 0x7FFFu + ((u >> 16) & 1u)) >> 16);
}

__device__ __forceinline__ void gld_lds16(const void* g, void* l) {
    __builtin_amdgcn_global_load_lds(
        (const __attribute__((address_space(1))) unsigned int*)g,
        (__attribute__((address_space(3))) unsigned int*)l, 16, 0, 0);
}

// ---------------- CSR build ----------------

__global__ void k_zero32(int* __restrict__ p, int n) {
    int i = blockIdx.x * blockDim.x + threadIdx.x;
    if (i < n) p[i] = 0;
}

__global__ void k_count(const int* __restrict__ dst, int* __restrict__ cnt) {
    int e = blockIdx.x * blockDim.x + threadIdx.x;
    if (e < N_EDGESC) atomicAdd(&cnt[dst[e]], 1);
}

__global__ __launch_bounds__(1024) void k_scan(const int* __restrict__ deg,
                                               int* __restrict__ rowstart) {
    __shared__ int ps[1024];
    int tid = threadIdx.x;
    const int CH = (N_NODESC + 1023) / 1024;
    int beg = tid * CH;
    int end = min(beg + CH, N_NODESC);
    int s = 0;
    for (int i = beg; i < end; i++) s += deg[i];
    ps[tid] = s;
    __syncthreads();
    for (int off = 1; off < 1024; off <<= 1) {
        int v = (tid >= off) ? ps[tid - off] : 0;
        __syncthreads();
        ps[tid] += v;
        __syncthreads();
    }
    int run = (tid == 0) ? 0 : ps[tid - 1];
    for (int i = beg; i < end; i++) { rowstart[i] = run; run += deg[i]; }
    if (tid == 1023) rowstart[N_NODESC] = ps[1023];
}

__global__ void k_fill(const int* __restrict__ src, const int* __restrict__ dst,
                       const int* __restrict__ rowstart, int* __restrict__ cur,
                       int* __restrict__ esrc) {
    int e = blockIdx.x * blockDim.x + threadIdx.x;
    if (e < N_EDGESC) {
        int d = dst[e];
        int pos = rowstart[d] + atomicAdd(&cur[d], 1);
        esrc[pos] = src[e];
    }
}

// ---------------- weight prep: W[k][n] f32 -> Wt[n][k] bf16, 10 matrices ----------------

__global__ __launch_bounds__(256) void k_wprep(const float* __restrict__ W1a,
                                               const float* __restrict__ W1b,
                                               const float* __restrict__ Ws1,
                                               const float* __restrict__ Ws2,
                                               unsigned short* __restrict__ Wt) {
    int i = blockIdx.x * blockDim.x + threadIdx.x;  // 10*65536 total
    if (i >= 10 * 65536) return;
    int m = i >> 16;
    int r = i & 65535;
    int n = r >> 8;
    int k = r & 255;
    int l = m >> 1, wsel = m & 1;
    const float* src = (l == 0) ? (wsel ? W1b : W1a)
                                : (wsel ? Ws2 + (size_t)(l - 1) * 65536
                                        : Ws1 + (size_t)(l - 1) * 65536);
    Wt[i] = f2bf(src[(size_t)k * 256 + n]);
}

// zero pad rows [50000, MPAD) of two bf16 buffers
__global__ void k_zeropad(unsigned short* __restrict__ b1,
                          unsigned short* __restrict__ b2) {
    int i = blockIdx.x * blockDim.x + threadIdx.x;
    int npad = (MPAD - N_NODESC) * DDIM;  // 12288
    if (i < npad) {
        b1[(size_t)N_NODESC * DDIM + i] = 0;
        b2[(size_t)N_NODESC * DDIM + i] = 0;
    }
}

// ---------------- mean aggregation ----------------
// layer 0: fp32 input -> bf16 out. one wave per node, lane: 4 feats (float4)
__global__ __launch_bounds__(256) void k_agg_f32(const float* __restrict__ X,
                                                 const int* __restrict__ esrc,
                                                 const int* __restrict__ rowstart,
                                                 unsigned short* __restrict__ Hout) {
    int node = blockIdx.x * 4 + (threadIdx.x >> 6);
    if (node >= N_NODESC) return;
    int lane = threadIdx.x & 63;
    int beg = rowstart[node];
    int end = rowstart[node + 1];
    float4 s = make_float4(0.f, 0.f, 0.f, 0.f);
    for (int j = beg; j < end; j++) {
        int sn = esrc[j];
        float4 v = *(const float4*)(X + (size_t)sn * DDIM + lane * 4);
        s.x += v.x; s.y += v.y; s.z += v.z; s.w += v.w;
    }
    float inv = (end > beg) ? 1.0f / (float)(end - beg) : 0.0f;
    float4 xv = *(const float4*)(X + (size_t)node * DDIM + lane * 4);
    ushort4 o;
    o.x = f2bf(xv.x + s.x * inv);
    o.y = f2bf(xv.y + s.y * inv);
    o.z = f2bf(xv.z + s.z * inv);
    o.w = f2bf(xv.w + s.w * inv);
    *(ushort4*)(Hout + (size_t)node * DDIM + lane * 4) = o;
}

// layers 1..4: bf16 -> bf16. one wave per node, lane: 4 feats (8B)  [R2 FIX]
__global__ __launch_bounds__(256) void k_agg_bf(const unsigned short* __restrict__ X,
                                                const int* __restrict__ esrc,
                                                const int* __restrict__ rowstart,
                                                unsigned short* __restrict__ Hout) {
    int node = blockIdx.x * 4 + (threadIdx.x >> 6);
    if (node >= N_NODESC) return;
    int lane = threadIdx.x & 63;
    int beg = rowstart[node];
    int end = rowstart[node + 1];
    float s0 = 0.f, s1 = 0.f, s2 = 0.f, s3 = 0.f;
    for (int j = beg; j < end; j++) {
        int sn = esrc[j];
        ushort4 v = *(const ushort4*)(X + (size_t)sn * DDIM + lane * 4);
        s0 += bf2f(v.x); s1 += bf2f(v.y); s2 += bf2f(v.z); s3 += bf2f(v.w);
    }
    float inv = (end > beg) ? 1.0f / (float)(end - beg) : 0.0f;
    ushort4 xv = *(const ushort4*)(X + (size_t)node * DDIM + lane * 4);
    ushort4 o;
    o.x = f2bf(bf2f(xv.x) + s0 * inv);
    o.y = f2bf(bf2f(xv.y) + s1 * inv);
    o.z = f2bf(bf2f(xv.z) + s2 * inv);
    o.w = f2bf(bf2f(xv.w) + s3 * inv);
    *(ushort4*)(Hout + (size_t)node * DDIM + lane * 4) = o;
}

// ---------------- bf16 MFMA GEMM: C = relu(A @ W + bias) ----------------
// A[MPAD][256] bf16 row-major, Wt[n][k] bf16 (pre-transposed), C[MPAD][256] bf16
// 128x128 tile, BK=32, 256 threads = 4 waves (2x2), 4x4 fragments/wave.

__global__ __launch_bounds__(256) void k_gemm_bf16(const unsigned short* __restrict__ A,
                                                   const unsigned short* __restrict__ Wt,
                                                   const float* __restrict__ bias,
                                                   unsigned short* __restrict__ C) {
    __shared__ unsigned short As[128 * 32];  // chunk-swizzled [row][kc]
    __shared__ unsigned short Bs[128 * 32];  // Wt tile, same layout (row = out col)

    const int tid = threadIdx.x;
    const int wv = tid >> 6;
    const int lane = tid & 63;
    const int bm = blockIdx.x;
    const int bn = blockIdx.y;

    const int wr = (wv >> 1) * 64;  // wave row offset
    const int wc = (wv & 1) * 64;   // wave col offset
    const int lr = lane & 15;
    const int lk = lane >> 4;

    f32x4 acc[4][4];
#pragma unroll
    for (int m = 0; m < 4; m++)
#pragma unroll
        for (int n = 0; n < 4; n++) acc[m][n] = (f32x4)(0.f);

    for (int k0 = 0; k0 < 256; k0 += 32) {
        // stage A and B tiles: 512 16B-chunks each; wave wv covers chunks
        // [wv*128, wv*128+128), 2 calls of 64 lanes each.
#pragma unroll
        for (int i = 0; i < 2; i++) {
            int c = wv * 128 + i * 64 + lane;
            int row = c >> 2;
            int kc = (c & 3) ^ ((row >> 1) & 3);  // inverse swizzle on source
            const unsigned short* ga = A + (size_t)(bm * 128 + row) * 256 + k0 + kc * 8;
            gld_lds16(ga, (void*)&As[(size_t)(wv * 128 + i * 64) * 8]);
            const unsigned short* gb = Wt + (size_t)(bn * 128 + row) * 256 + k0 + kc * 8;
            gld_lds16(gb, (void*)&Bs[(size_t)(wv * 128 + i * 64) * 8]);
        }
        __syncthreads();

        bf16x8 af[4], bfr[4];
#pragma unroll
        for (int m = 0; m < 4; m++) {
            int row = wr + m * 16 + lr;
            int off = row * 4 + (lk ^ ((row >> 1) & 3));
            af[m] = ((const bf16x8*)As)[off];
        }
#pragma unroll
        for (int n = 0; n < 4; n++) {
            int row = wc + n * 16 + lr;
            int off = row * 4 + (lk ^ ((row >> 1) & 3));
            bfr[n] = ((const bf16x8*)Bs)[off];
        }
#pragma unroll
        for (int m = 0; m < 4; m++)
#pragma unroll
            for (int n = 0; n < 4; n++)
                acc[m][n] = __builtin_amdgcn_mfma_f32_16x16x32_bf16(af[m], bfr[n],
                                                                    acc[m][n], 0, 0, 0);
        __syncthreads();
    }

    // epilogue: D row=(lane>>4)*4+i, col=lane&15 within each 16x16 fragment
#pragma unroll
    for (int n = 0; n < 4; n++) {
        int col = bn * 128 + wc + n * 16 + lr;
        float bv = bias[col];
#pragma unroll
        for (int m = 0; m < 4; m++) {
#pragma unroll
            for (int i = 0; i < 4; i++) {
                int row = bm * 128 + wr + m * 16 + lk * 4 + i;
                float v = fmaxf(acc[m][n][i] + bv, 0.f);
                C[(size_t)row * 256 + col] = f2bf(v);
            }
        }
    }
}

// ---------------- BN statistics + normalize (bf16) ----------------

__global__ __launch_bounds__(256) void k_colreduce_bf(const unsigned short* __restrict__ H,
                                                      float* __restrict__ cs,
                                                      float* __restrict__ css, int M) {
    int d = threadIdx.x;
    float s = 0.f, ss = 0.f;
    for (int n = blockIdx.x; n < M; n += gridDim.x) {
        float v = bf2f(H[(size_t)n * DDIM + d]);
        s += v;
        ss += v * v;
    }
    atomicAdd(&cs[d], s);
    atomicAdd(&css[d], ss);
}

__global__ __launch_bounds__(256) void k_bn_bf(const unsigned short* __restrict__ H,
                                               const float* __restrict__ cs,
                                               const float* __restrict__ css,
                                               const float* __restrict__ gamma,
                                               const float* __restrict__ beta,
                                               unsigned short* __restrict__ Y, int M) {
    const float invN = 1.0f / (float)M;
    int total = M * (DDIM / 8);
    for (int i = blockIdx.x * blockDim.x + threadIdx.x; i < total;
         i += gridDim.x * blockDim.x) {
        int d8 = (i & 31) * 8;
        u16x8 h = ((const u16x8*)H)[i];
        u16x8 o;
#pragma unroll
        for (int j = 0; j < 8; j++) {
            int d = d8 + j;
            float mu = cs[d] * invN;
            float var = css[d] * invN - mu * mu;
            float sc = gamma[d] * rsqrtf(var + BN_EPSF);
            o[j] = f2bf(sc * (bf2f(h[j]) - mu) + beta[d]);
        }
        ((u16x8*)Y)[i] = o;
    }
}

// ---------------- classification head ----------------

__global__ __launch_bounds__(256) void k_head(const unsigned short* __restrict__ Y,
                                              const int* __restrict__ counts,
                                              const float* __restrict__ fcW1,
                                              const float* __restrict__ fcb1,
                                              const float* __restrict__ fcW2,
                                              const float* __restrict__ fcb2,
                                              float* __restrict__ out) {
    int g = blockIdx.x;
    __shared__ float row[DDIM];
    __shared__ float gv[DDIM];
    __shared__ float logits[NCLS];
    __shared__ int lastIdx;
    if (threadIdx.x == 0) {
        int s = 0;
        for (int i = 0; i <= g; i++) s += counts[i];
        lastIdx = s - 1;
    }
    __syncthreads();
    int j = threadIdx.x;
    row[j] = bf2f(Y[(size_t)lastIdx * DDIM + j]);
    __syncthreads();
    float acc = fcb1[j];
    for (int d = 0; d < DDIM; d++) acc += row[d] * fcW1[(size_t)d * DDIM + j];
    gv[j] = fmaxf(acc, 0.f);
    __syncthreads();
    if (j < NCLS) {
        float a = fcb2[j];
        for (int d = 0; d < DDIM; d++) a += gv[d] * fcW2[(size_t)d * NCLS + j];
        logits[j] = a;
    }
    __syncthreads();
    if (j == 0) {
        float m = -1e30f;
        for (int c = 0; c < NCLS; c++) m = fmaxf(m, logits[c]);
        float se = 0.f;
        for (int c = 0; c < NCLS; c++) se += expf(logits[c] - m);
        float lse = m + logf(se);
        for (int c = 0; c < NCLS; c++) out[g * NCLS + c] = logits[c] - lse;
    }
}

// ---------------- launcher ----------------

extern "C" void kernel_launch(void* const* d_in, const int* in_sizes, int n_in,
                              void* d_out, int out_size, void* d_ws, size_t ws_size,
                              hipStream_t stream) {
    const float* x    = (const float*)d_in[0];
    const int* src    = (const int*)d_in[1];
    const int* dst    = (const int*)d_in[2];
    const int* counts = (const int*)d_in[3];
    const float* W1a  = (const float*)d_in[4];
    const float* b1a  = (const float*)d_in[5];
    const float* W1b  = (const float*)d_in[6];
    const float* b1b  = (const float*)d_in[7];
    const float* g1   = (const float*)d_in[8];
    const float* be1  = (const float*)d_in[9];
    const float* Ws1  = (const float*)d_in[10];
    const float* bs1  = (const float*)d_in[11];
    const float* Ws2  = (const float*)d_in[12];
    const float* bs2  = (const float*)d_in[13];
    const float* gms  = (const float*)d_in[14];
    const float* bts  = (const float*)d_in[15];
    const float* fcW1 = (const float*)d_in[16];
    const float* fcb1 = (const float*)d_in[17];
    const float* fcW2 = (const float*)d_in[18];
    const float* fcb2 = (const float*)d_in[19];
    float* out = (float*)d_out;

    char* ws = (char*)d_ws;
    const size_t BUF = (size_t)MPAD * DDIM * 2;  // 25,624,576 B
    unsigned short* B0 = (unsigned short*)(ws);
    unsigned short* B1 = (unsigned short*)(ws + BUF);
    unsigned short* B2 = (unsigned short*)(ws + 2 * BUF);
    unsigned short* Wt = (unsigned short*)(ws + 3 * BUF);          // 1,310,720 B
    int* rowstart      = (int*)(ws + 3 * BUF + 1310720);           // 200,064 B
    int* cursor        = (int*)(ws + 3 * BUF + 1510784);           // 200,064 B
    int* esrc          = (int*)(ws + 3 * BUF + 1710848);           // 1,600,000 B
    float* colsum      = (float*)(ws + 3 * BUF + 3310848);         // 2 KB

    // ---- CSR build ----
    k_zero32<<<dim3((N_NODESC + 255) / 256), 256, 0, stream>>>(cursor, N_NODESC);
    k_count<<<dim3((N_EDGESC + 255) / 256), 256, 0, stream>>>(dst, cursor);
    k_scan<<<1, 1024, 0, stream>>>(cursor, rowstart);
    k_zero32<<<dim3((N_NODESC + 255) / 256), 256, 0, stream>>>(cursor, N_NODESC);
    k_fill<<<dim3((N_EDGESC + 255) / 256), 256, 0, stream>>>(src, dst, rowstart,
                                                             cursor, esrc);

    // ---- weight prep + pad zeroing ----
    k_wprep<<<dim3((10 * 65536 + 255) / 256), 256, 0, stream>>>(W1a, W1b, Ws1, Ws2, Wt);
    k_zeropad<<<dim3(((MPAD - N_NODESC) * DDIM + 255) / 256), 256, 0, stream>>>(B1, B2);

    // ---- 5 GIN layers ----
    for (int l = 0; l < 5; ++l) {
        const float* B1b = (l == 0) ? b1a : bs1 + (l - 1) * 256;
        const float* B2b = (l == 0) ? b1b : bs2 + (l - 1) * 256;
        const float* GA  = (l == 0) ? g1 : gms + (l - 1) * 256;
        const float* BE  = (l == 0) ? be1 : bts + (l - 1) * 256;
        const unsigned short* Wt1 = Wt + (size_t)(l * 2) * 65536;
        const unsigned short* Wt2 = Wt + (size_t)(l * 2 + 1) * 65536;

        if (l == 0)
            k_agg_f32<<<dim3(12500), 256, 0, stream>>>(x, esrc, rowstart, B1);
        else
            k_agg_bf<<<dim3(12500), 256, 0, stream>>>(B0, esrc, rowstart, B1);

        k_gemm_bf16<<<dim3(MPAD / 128, 2), 256, 0, stream>>>(B1, Wt1, B1b, B2);
        k_zero32<<<1, 512, 0, stream>>>((int*)colsum, 512);
        k_gemm_bf16<<<dim3(MPAD / 128, 2), 256, 0, stream>>>(B2, Wt2, B2b, B1);
        k_colreduce_bf<<<dim3(512), 256, 0, stream>>>(B1, colsum, colsum + 256,
                                                      N_NODESC);
        k_bn_bf<<<dim3(2048), 256, 0, stream>>>(B1, colsum, colsum + 256, GA, BE, B0,
                                                N_NODESC);
    }

    // ---- head ----
    k_head<<<dim3(N_GRAPHSC), 256, 0, stream>>>(B0, counts, fcW1, fcb1, fcW2, fcb2,
                                                out);
}

// Round 4
// 702.411 us; speedup vs baseline: 2.4372x; 1.2583x over previous
//
#include <hip/hip_runtime.h>
#include <hip/hip_bf16.h>

#define N_NODESC 50000
#define N_EDGESC 400000
#define N_GRAPHSC 250
#define DDIM 256
#define NCLS 10
#define BN_EPSF 1e-5f
#define MPAD 50048   // 391 * 128
#define NBLK_SCAN 196

typedef __attribute__((ext_vector_type(4))) float f32x4;
typedef __attribute__((ext_vector_type(8))) short bf16x8;
typedef __attribute__((ext_vector_type(8))) unsigned short u16x8;

__device__ __forceinline__ float bf2f(unsigned short h) {
    union { unsigned int u; float f; } c;
    c.u = ((unsigned int)h) << 16;
    return c.f;
}
__device__ __forceinline__ unsigned short f2bf(float f) {
    union { float f; unsigned int u; } c;
    c.f = f;
    unsigned int u = c.u;
    return (unsigned short)((u + 0x7FFFu + ((u >> 16) & 1u)) >> 16);
}

__device__ __forceinline__ void gld_lds16(const void* g, void* l) {
    __builtin_amdgcn_global_load_lds(
        (const __attribute__((address_space(1))) unsigned int*)g,
        (__attribute__((address_space(3))) unsigned int*)l, 16, 0, 0);
}

// ---------------- CSR build ----------------

__global__ void k_zero32(int* __restrict__ p, int n) {
    int i = blockIdx.x * blockDim.x + threadIdx.x;
    if (i < n) p[i] = 0;
}

__global__ void k_count(const int* __restrict__ dst, int* __restrict__ cnt) {
    int e = blockIdx.x * blockDim.x + threadIdx.x;
    if (e < N_EDGESC) atomicAdd(&cnt[dst[e]], 1);
}

// parallel exclusive scan over deg[50000] -> rowstart, block sums -> bsum
__global__ __launch_bounds__(256) void k_scan1(const int* __restrict__ deg,
                                               int* __restrict__ rowstart,
                                               int* __restrict__ bsum) {
    __shared__ int sh[256];
    int tid = threadIdx.x;
    int i = blockIdx.x * 256 + tid;
    int v = (i < N_NODESC) ? deg[i] : 0;
    sh[tid] = v;
    __syncthreads();
    for (int off = 1; off < 256; off <<= 1) {
        int t = (tid >= off) ? sh[tid - off] : 0;
        __syncthreads();
        sh[tid] += t;
        __syncthreads();
    }
    if (i < N_NODESC) rowstart[i] = sh[tid] - v;  // exclusive within block
    if (tid == 255) bsum[blockIdx.x] = sh[255];
}

__global__ __launch_bounds__(256) void k_scan2(int* __restrict__ rowstart,
                                               const int* __restrict__ bsum) {
    __shared__ int sh[256];
    int tid = threadIdx.x;
    sh[tid] = (tid < NBLK_SCAN) ? bsum[tid] : 0;
    __syncthreads();
    for (int off = 1; off < 256; off <<= 1) {
        int t = (tid >= off) ? sh[tid - off] : 0;
        __syncthreads();
        sh[tid] += t;
        __syncthreads();
    }
    int i = blockIdx.x * 256 + tid;
    if (blockIdx.x > 0 && i < N_NODESC) rowstart[i] += sh[blockIdx.x - 1];
    if (i == 0) rowstart[N_NODESC] = N_EDGESC;  // total edges is a constant
}

__global__ void k_fill(const int* __restrict__ src, const int* __restrict__ dst,
                       const int* __restrict__ rowstart, int* __restrict__ cur,
                       int* __restrict__ esrc) {
    int e = blockIdx.x * blockDim.x + threadIdx.x;
    if (e < N_EDGESC) {
        int d = dst[e];
        int pos = rowstart[d] + atomicAdd(&cur[d], 1);
        esrc[pos] = src[e];
    }
}

// ---------------- weight prep: W[k][n] f32 -> Wt[n][k] bf16, 10 matrices ----------------

__global__ __launch_bounds__(256) void k_wprep(const float* __restrict__ W1a,
                                               const float* __restrict__ W1b,
                                               const float* __restrict__ Ws1,
                                               const float* __restrict__ Ws2,
                                               unsigned short* __restrict__ Wt) {
    int i = blockIdx.x * blockDim.x + threadIdx.x;  // 10*65536 total
    if (i >= 10 * 65536) return;
    int m = i >> 16;
    int r = i & 65535;
    int n = r >> 8;
    int k = r & 255;
    int l = m >> 1, wsel = m & 1;
    const float* src = (l == 0) ? (wsel ? W1b : W1a)
                                : (wsel ? Ws2 + (size_t)(l - 1) * 65536
                                        : Ws1 + (size_t)(l - 1) * 65536);
    Wt[i] = f2bf(src[(size_t)k * 256 + n]);
}

// zero pad rows [50000, MPAD) of two bf16 buffers
__global__ void k_zeropad(unsigned short* __restrict__ b1,
                          unsigned short* __restrict__ b2) {
    int i = blockIdx.x * blockDim.x + threadIdx.x;
    int npad = (MPAD - N_NODESC) * DDIM;  // 12288
    if (i < npad) {
        b1[(size_t)N_NODESC * DDIM + i] = 0;
        b2[(size_t)N_NODESC * DDIM + i] = 0;
    }
}

// ---------------- mean aggregation ----------------
// layer 0: fp32 input -> bf16 out (no BN on raw input). lane: 4 feats
__global__ __launch_bounds__(256) void k_agg_f32(const float* __restrict__ X,
                                                 const int* __restrict__ esrc,
                                                 const int* __restrict__ rowstart,
                                                 unsigned short* __restrict__ Hout) {
    int node = blockIdx.x * 4 + (threadIdx.x >> 6);
    if (node >= N_NODESC) return;
    int lane = threadIdx.x & 63;
    int beg = rowstart[node];
    int end = rowstart[node + 1];
    float4 s = make_float4(0.f, 0.f, 0.f, 0.f);
    for (int j = beg; j < end; j++) {
        int sn = esrc[j];
        float4 v = *(const float4*)(X + (size_t)sn * DDIM + lane * 4);
        s.x += v.x; s.y += v.y; s.z += v.z; s.w += v.w;
    }
    float inv = (end > beg) ? 1.0f / (float)(end - beg) : 0.0f;
    float4 xv = *(const float4*)(X + (size_t)node * DDIM + lane * 4);
    ushort4 o;
    o.x = f2bf(xv.x + s.x * inv);
    o.y = f2bf(xv.y + s.y * inv);
    o.z = f2bf(xv.z + s.z * inv);
    o.w = f2bf(xv.w + s.w * inv);
    *(ushort4*)(Hout + (size_t)node * DDIM + lane * 4) = o;
}

// layers 1..4: input = RAW previous-layer h (bf16) + its BN stats.
// BN is per-column affine norm(v) = sc*v + t, and mean-agg commutes with it:
//   out = sc*(x_node + inv*sum_src) + t*(deg>0 ? 2 : 1)
__global__ __launch_bounds__(256) void k_agg_bf(const unsigned short* __restrict__ X,
                                                const int* __restrict__ esrc,
                                                const int* __restrict__ rowstart,
                                                const float* __restrict__ stat,  // [512]
                                                const float* __restrict__ gamma,
                                                const float* __restrict__ beta,
                                                unsigned short* __restrict__ Hout) {
    int node = blockIdx.x * 4 + (threadIdx.x >> 6);
    if (node >= N_NODESC) return;
    int lane = threadIdx.x & 63;
    int d0 = lane * 4;
    const float invN = 1.0f / (float)N_NODESC;
    float sc[4], tt[4];
#pragma unroll
    for (int q = 0; q < 4; q++) {
        float mu = stat[d0 + q] * invN;
        float var = stat[256 + d0 + q] * invN - mu * mu;
        float s = gamma[d0 + q] * rsqrtf(var + BN_EPSF);
        sc[q] = s;
        tt[q] = beta[d0 + q] - s * mu;
    }
    int beg = rowstart[node];
    int end = rowstart[node + 1];
    float s0 = 0.f, s1 = 0.f, s2 = 0.f, s3 = 0.f;
    for (int j = beg; j < end; j++) {
        int sn = esrc[j];
        ushort4 v = *(const ushort4*)(X + (size_t)sn * DDIM + d0);
        s0 += bf2f(v.x); s1 += bf2f(v.y); s2 += bf2f(v.z); s3 += bf2f(v.w);
    }
    float inv = (end > beg) ? 1.0f / (float)(end - beg) : 0.0f;
    float cnt = (end > beg) ? 2.0f : 1.0f;
    ushort4 xv = *(const ushort4*)(X + (size_t)node * DDIM + d0);
    ushort4 o;
    o.x = f2bf(sc[0] * (bf2f(xv.x) + s0 * inv) + tt[0] * cnt);
    o.y = f2bf(sc[1] * (bf2f(xv.y) + s1 * inv) + tt[1] * cnt);
    o.z = f2bf(sc[2] * (bf2f(xv.z) + s2 * inv) + tt[2] * cnt);
    o.w = f2bf(sc[3] * (bf2f(xv.w) + s3 * inv) + tt[3] * cnt);
    *(ushort4*)(Hout + (size_t)node * DDIM + d0) = o;
}

// ---------------- bf16 MFMA GEMM: C = relu(A @ W + bias), optional col stats ----------------
// A[MPAD][256] bf16 row-major, Wt[n][k] bf16 (pre-transposed), C[MPAD][256] bf16
// 128x128 tile, BK=32, 256 threads = 4 waves (2x2), 4x4 fragments/wave.

__global__ __launch_bounds__(256) void k_gemm_bf16(const unsigned short* __restrict__ A,
                                                   const unsigned short* __restrict__ Wt,
                                                   const float* __restrict__ bias,
                                                   unsigned short* __restrict__ C,
                                                   float* __restrict__ stat) {
    __shared__ unsigned short As[128 * 32];  // chunk-swizzled [row][kc]
    __shared__ unsigned short Bs[128 * 32];  // Wt tile, same layout (row = out col)

    const int tid = threadIdx.x;
    const int wv = tid >> 6;
    const int lane = tid & 63;
    const int bm = blockIdx.x;
    const int bn = blockIdx.y;

    const int wr = (wv >> 1) * 64;  // wave row offset
    const int wc = (wv & 1) * 64;   // wave col offset
    const int lr = lane & 15;
    const int lk = lane >> 4;

    f32x4 acc[4][4];
#pragma unroll
    for (int m = 0; m < 4; m++)
#pragma unroll
        for (int n = 0; n < 4; n++) acc[m][n] = (f32x4)(0.f);

    for (int k0 = 0; k0 < 256; k0 += 32) {
#pragma unroll
        for (int i = 0; i < 2; i++) {
            int c = wv * 128 + i * 64 + lane;
            int row = c >> 2;
            int kc = (c & 3) ^ ((row >> 1) & 3);  // inverse swizzle on source
            const unsigned short* ga = A + (size_t)(bm * 128 + row) * 256 + k0 + kc * 8;
            gld_lds16(ga, (void*)&As[(size_t)(wv * 128 + i * 64) * 8]);
            const unsigned short* gb = Wt + (size_t)(bn * 128 + row) * 256 + k0 + kc * 8;
            gld_lds16(gb, (void*)&Bs[(size_t)(wv * 128 + i * 64) * 8]);
        }
        __syncthreads();

        bf16x8 af[4], bfr[4];
#pragma unroll
        for (int m = 0; m < 4; m++) {
            int row = wr + m * 16 + lr;
            int off = row * 4 + (lk ^ ((row >> 1) & 3));
            af[m] = ((const bf16x8*)As)[off];
        }
#pragma unroll
        for (int n = 0; n < 4; n++) {
            int row = wc + n * 16 + lr;
            int off = row * 4 + (lk ^ ((row >> 1) & 3));
            bfr[n] = ((const bf16x8*)Bs)[off];
        }
#pragma unroll
        for (int m = 0; m < 4; m++)
#pragma unroll
            for (int n = 0; n < 4; n++)
                acc[m][n] = __builtin_amdgcn_mfma_f32_16x16x32_bf16(af[m], bfr[n],
                                                                    acc[m][n], 0, 0, 0);
        __syncthreads();
    }

    // epilogue: D row=(lane>>4)*4+i, col=lane&15 within each 16x16 fragment
#pragma unroll
    for (int n = 0; n < 4; n++) {
        int col = bn * 128 + wc + n * 16 + lr;
        float bv = bias[col];
        float sp = 0.f, ssp = 0.f;
#pragma unroll
        for (int m = 0; m < 4; m++) {
#pragma unroll
            for (int i = 0; i < 4; i++) {
                int row = bm * 128 + wr + m * 16 + lk * 4 + i;
                float v = fmaxf(acc[m][n][i] + bv, 0.f);
                C[(size_t)row * 256 + col] = f2bf(v);
                if (row < N_NODESC) { sp += v; ssp += v * v; }
            }
        }
        if (stat) {
            sp += __shfl_xor(sp, 16);
            sp += __shfl_xor(sp, 32);
            ssp += __shfl_xor(ssp, 16);
            ssp += __shfl_xor(ssp, 32);
            if (lane < 16) {
                atomicAdd(&stat[col], sp);
                atomicAdd(&stat[256 + col], ssp);
            }
        }
    }
}

// ---------------- classification head (applies final BN inline) ----------------

__global__ __launch_bounds__(256) void k_head(const unsigned short* __restrict__ Y,
                                              const int* __restrict__ counts,
                                              const float* __restrict__ stat,
                                              const float* __restrict__ gamma,
                                              const float* __restrict__ beta,
                                              const float* __restrict__ fcW1,
                                              const float* __restrict__ fcb1,
                                              const float* __restrict__ fcW2,
                                              const float* __restrict__ fcb2,
                                              float* __restrict__ out) {
    int g = blockIdx.x;
    __shared__ float row[DDIM];
    __shared__ float gv[DDIM];
    __shared__ float logits[NCLS];
    __shared__ int lastIdx;
    if (threadIdx.x == 0) {
        int s = 0;
        for (int i = 0; i <= g; i++) s += counts[i];
        lastIdx = s - 1;
    }
    __syncthreads();
    int j = threadIdx.x;
    const float invN = 1.0f / (float)N_NODESC;
    float mu = stat[j] * invN;
    float var = stat[256 + j] * invN - mu * mu;
    float sc = gamma[j] * rsqrtf(var + BN_EPSF);
    row[j] = sc * (bf2f(Y[(size_t)lastIdx * DDIM + j]) - mu) + beta[j];
    __syncthreads();
    float acc = fcb1[j];
    for (int d = 0; d < DDIM; d++) acc += row[d] * fcW1[(size_t)d * DDIM + j];
    gv[j] = fmaxf(acc, 0.f);
    __syncthreads();
    if (j < NCLS) {
        float a = fcb2[j];
        for (int d = 0; d < DDIM; d++) a += gv[d] * fcW2[(size_t)d * NCLS + j];
        logits[j] = a;
    }
    __syncthreads();
    if (j == 0) {
        float m = -1e30f;
        for (int c = 0; c < NCLS; c++) m = fmaxf(m, logits[c]);
        float se = 0.f;
        for (int c = 0; c < NCLS; c++) se += expf(logits[c] - m);
        float lse = m + logf(se);
        for (int c = 0; c < NCLS; c++) out[g * NCLS + c] = logits[c] - lse;
    }
}

// ---------------- launcher ----------------

extern "C" void kernel_launch(void* const* d_in, const int* in_sizes, int n_in,
                              void* d_out, int out_size, void* d_ws, size_t ws_size,
                              hipStream_t stream) {
    const float* x    = (const float*)d_in[0];
    const int* src    = (const int*)d_in[1];
    const int* dst    = (const int*)d_in[2];
    const int* counts = (const int*)d_in[3];
    const float* W1a  = (const float*)d_in[4];
    const float* b1a  = (const float*)d_in[5];
    const float* W1b  = (const float*)d_in[6];
    const float* b1b  = (const float*)d_in[7];
    const float* g1   = (const float*)d_in[8];
    const float* be1  = (const float*)d_in[9];
    const float* Ws1  = (const float*)d_in[10];
    const float* bs1  = (const float*)d_in[11];
    const float* Ws2  = (const float*)d_in[12];
    const float* bs2  = (const float*)d_in[13];
    const float* gms  = (const float*)d_in[14];
    const float* bts  = (const float*)d_in[15];
    const float* fcW1 = (const float*)d_in[16];
    const float* fcb1 = (const float*)d_in[17];
    const float* fcW2 = (const float*)d_in[18];
    const float* fcb2 = (const float*)d_in[19];
    float* out = (float*)d_out;

    char* ws = (char*)d_ws;
    const size_t BUF = (size_t)MPAD * DDIM * 2;  // 25,624,576 B
    unsigned short* B0 = (unsigned short*)(ws);
    unsigned short* B1 = (unsigned short*)(ws + BUF);
    unsigned short* B2 = (unsigned short*)(ws + 2 * BUF);
    unsigned short* Wt = (unsigned short*)(ws + 3 * BUF);          // 1,310,720 B
    int* rowstart      = (int*)(ws + 3 * BUF + 1310720);           // 200,064 B
    int* cursor        = (int*)(ws + 3 * BUF + 1510784);           // 200,064 B
    int* esrc          = (int*)(ws + 3 * BUF + 1710848);           // 1,600,000 B
    float* colsum      = (float*)(ws + 3 * BUF + 3310848);         // 2,048 B
    int* bsum          = (int*)(ws + 3 * BUF + 3312896);           // 784 B

    // ---- CSR build ----
    k_zero32<<<dim3((N_NODESC + 255) / 256), 256, 0, stream>>>(cursor, N_NODESC);
    k_count<<<dim3((N_EDGESC + 255) / 256), 256, 0, stream>>>(dst, cursor);
    k_scan1<<<dim3(NBLK_SCAN), 256, 0, stream>>>(cursor, rowstart, bsum);
    k_scan2<<<dim3(NBLK_SCAN), 256, 0, stream>>>(rowstart, bsum);
    k_zero32<<<dim3((N_NODESC + 255) / 256), 256, 0, stream>>>(cursor, N_NODESC);
    k_fill<<<dim3((N_EDGESC + 255) / 256), 256, 0, stream>>>(src, dst, rowstart,
                                                             cursor, esrc);

    // ---- weight prep + pad zeroing ----
    k_wprep<<<dim3((10 * 65536 + 255) / 256), 256, 0, stream>>>(W1a, W1b, Ws1, Ws2, Wt);
    k_zeropad<<<dim3(((MPAD - N_NODESC) * DDIM + 255) / 256), 256, 0, stream>>>(B1, B2);

    // ---- 5 GIN layers (BN of layer l applied inside agg of layer l+1 / head) ----
    for (int l = 0; l < 5; ++l) {
        const float* B1b = (l == 0) ? b1a : bs1 + (l - 1) * 256;
        const float* B2b = (l == 0) ? b1b : bs2 + (l - 1) * 256;
        const unsigned short* Wt1 = Wt + (size_t)(l * 2) * 65536;
        const unsigned short* Wt2 = Wt + (size_t)(l * 2 + 1) * 65536;

        if (l == 0) {
            k_agg_f32<<<dim3(12500), 256, 0, stream>>>(x, esrc, rowstart, B1);
        } else {
            // stats/gamma/beta of the PREVIOUS layer
            const float* GA = (l == 1) ? g1 : gms + (l - 2) * 256;
            const float* BE = (l == 1) ? be1 : bts + (l - 2) * 256;
            k_agg_bf<<<dim3(12500), 256, 0, stream>>>(B0, esrc, rowstart, colsum,
                                                      GA, BE, B1);
        }

        k_gemm_bf16<<<dim3(MPAD / 128, 2), 256, 0, stream>>>(B1, Wt1, B1b, B2,
                                                             nullptr);
        k_zero32<<<1, 512, 0, stream>>>((int*)colsum, 512);
        k_gemm_bf16<<<dim3(MPAD / 128, 2), 256, 0, stream>>>(B2, Wt2, B2b, B0,
                                                             colsum);
    }

    // ---- head (applies layer-4 BN inline) ----
    k_head<<<dim3(N_GRAPHSC), 256, 0, stream>>>(B0, counts, colsum,
                                                gms + 3 * 256, bts + 3 * 256,
                                                fcW1, fcb1, fcW2, fcb2, out);
}

// Round 5
// 572.580 us; speedup vs baseline: 2.9899x; 1.2267x over previous
//
#include <hip/hip_runtime.h>
#include <hip/hip_bf16.h>

#define N_NODESC 50000
#define N_EDGESC 400000
#define N_GRAPHSC 250
#define DDIM 256
#define NCLS 10
#define BN_EPSF 1e-5f
#define MPAD 50048   // 391 * 128
#define NBLK_SCAN 196

typedef __attribute__((ext_vector_type(4))) float f32x4;
typedef __attribute__((ext_vector_type(8))) short bf16x8;
typedef __attribute__((ext_vector_type(8))) unsigned short u16x8;

__device__ __forceinline__ float bf2f(unsigned short h) {
    union { unsigned int u; float f; } c;
    c.u = ((unsigned int)h) << 16;
    return c.f;
}
__device__ __forceinline__ unsigned short f2bf(float f) {
    union { float f; unsigned int u; } c;
    c.f = f;
    unsigned int u = c.u;
    return (unsigned short)((u + 0x7FFFu + ((u >> 16) & 1u)) >> 16);
}

__device__ __forceinline__ void gld_lds16(const void* g, void* l) {
    __builtin_amdgcn_global_load_lds(
        (const __attribute__((address_space(1))) unsigned int*)g,
        (__attribute__((address_space(3))) unsigned int*)l, 16, 0, 0);
}

// ---------------- CSR build ----------------

__global__ void k_zero32(int* __restrict__ p, int n) {
    int i = blockIdx.x * blockDim.x + threadIdx.x;
    if (i < n) p[i] = 0;
}

__global__ void k_count(const int* __restrict__ dst, int* __restrict__ cnt) {
    int e = blockIdx.x * blockDim.x + threadIdx.x;
    if (e < N_EDGESC) atomicAdd(&cnt[dst[e]], 1);
}

__global__ __launch_bounds__(256) void k_scan1(const int* __restrict__ deg,
                                               int* __restrict__ rowstart,
                                               int* __restrict__ bsum) {
    __shared__ int sh[256];
    int tid = threadIdx.x;
    int i = blockIdx.x * 256 + tid;
    int v = (i < N_NODESC) ? deg[i] : 0;
    sh[tid] = v;
    __syncthreads();
    for (int off = 1; off < 256; off <<= 1) {
        int t = (tid >= off) ? sh[tid - off] : 0;
        __syncthreads();
        sh[tid] += t;
        __syncthreads();
    }
    if (i < N_NODESC) rowstart[i] = sh[tid] - v;
    if (tid == 255) bsum[blockIdx.x] = sh[255];
}

__global__ __launch_bounds__(256) void k_scan2(int* __restrict__ rowstart,
                                               const int* __restrict__ bsum) {
    __shared__ int sh[256];
    int tid = threadIdx.x;
    sh[tid] = (tid < NBLK_SCAN) ? bsum[tid] : 0;
    __syncthreads();
    for (int off = 1; off < 256; off <<= 1) {
        int t = (tid >= off) ? sh[tid - off] : 0;
        __syncthreads();
        sh[tid] += t;
        __syncthreads();
    }
    int i = blockIdx.x * 256 + tid;
    if (blockIdx.x > 0 && i < N_NODESC) rowstart[i] += sh[blockIdx.x - 1];
    if (i == 0) rowstart[N_NODESC] = N_EDGESC;
}

__global__ void k_fill(const int* __restrict__ src, const int* __restrict__ dst,
                       const int* __restrict__ rowstart, int* __restrict__ cur,
                       int* __restrict__ esrc) {
    int e = blockIdx.x * blockDim.x + threadIdx.x;
    if (e < N_EDGESC) {
        int d = dst[e];
        int pos = rowstart[d] + atomicAdd(&cur[d], 1);
        esrc[pos] = src[e];
    }
}

// ---------------- weight prep: W[k][n] f32 -> Wt[n][k] bf16, 10 matrices ----------------

__global__ __launch_bounds__(256) void k_wprep(const float* __restrict__ W1a,
                                               const float* __restrict__ W1b,
                                               const float* __restrict__ Ws1,
                                               const float* __restrict__ Ws2,
                                               unsigned short* __restrict__ Wt) {
    int i = blockIdx.x * blockDim.x + threadIdx.x;
    if (i >= 10 * 65536) return;
    int m = i >> 16;
    int r = i & 65535;
    int n = r >> 8;
    int k = r & 255;
    int l = m >> 1, wsel = m & 1;
    const float* src = (l == 0) ? (wsel ? W1b : W1a)
                                : (wsel ? Ws2 + (size_t)(l - 1) * 65536
                                        : Ws1 + (size_t)(l - 1) * 65536);
    Wt[i] = f2bf(src[(size_t)k * 256 + n]);
}

// x fp32 -> bf16
__global__ __launch_bounds__(256) void k_xbf(const float* __restrict__ X,
                                             unsigned short* __restrict__ Y) {
    int i = blockIdx.x * 256 + threadIdx.x;  // one float4 each
    if (i < N_NODESC * 64) {
        float4 v = ((const float4*)X)[i];
        ushort4 o;
        o.x = f2bf(v.x); o.y = f2bf(v.y); o.z = f2bf(v.z); o.w = f2bf(v.w);
        ((ushort4*)Y)[i] = o;
    }
}

// zero pad rows [50000, MPAD) of B1 (GEMM input buffer)
__global__ void k_zeropad(unsigned short* __restrict__ b1) {
    int i = blockIdx.x * blockDim.x + threadIdx.x;
    int npad = (MPAD - N_NODESC) * DDIM;
    if (i < npad) b1[(size_t)N_NODESC * DDIM + i] = 0;
}

// ---------------- mean aggregation + (optional) previous layer's BN ----------------
// BN is per-column affine norm(v)=sc*v+t; mean-agg commutes:
//   out = sc*(x_node + inv*sum_src) + t*(deg>0 ? 2 : 1)
// stat==nullptr -> plain agg (layer 0). Edge loop unrolled x2 for MLP.
__global__ __launch_bounds__(256) void k_agg_bf(const unsigned short* __restrict__ X,
                                                const int* __restrict__ esrc,
                                                const int* __restrict__ rowstart,
                                                const float* __restrict__ stat,
                                                const float* __restrict__ gamma,
                                                const float* __restrict__ beta,
                                                unsigned short* __restrict__ Hout) {
    int node = blockIdx.x * 4 + (threadIdx.x >> 6);
    if (node >= N_NODESC) return;
    int lane = threadIdx.x & 63;
    int d0 = lane * 4;
    float sc[4], tt[4];
    if (stat) {
        const float invN = 1.0f / (float)N_NODESC;
#pragma unroll
        for (int q = 0; q < 4; q++) {
            float mu = stat[d0 + q] * invN;
            float var = stat[256 + d0 + q] * invN - mu * mu;
            float s = gamma[d0 + q] * rsqrtf(var + BN_EPSF);
            sc[q] = s;
            tt[q] = beta[d0 + q] - s * mu;
        }
    } else {
#pragma unroll
        for (int q = 0; q < 4; q++) { sc[q] = 1.f; tt[q] = 0.f; }
    }
    int beg = rowstart[node];
    int end = rowstart[node + 1];
    float a0 = 0.f, a1 = 0.f, a2 = 0.f, a3 = 0.f;
    float b0 = 0.f, b1 = 0.f, b2 = 0.f, b3 = 0.f;
    int j = beg;
    for (; j + 2 <= end; j += 2) {
        int sn0 = esrc[j];
        int sn1 = esrc[j + 1];
        ushort4 v0 = *(const ushort4*)(X + (size_t)sn0 * DDIM + d0);
        ushort4 v1 = *(const ushort4*)(X + (size_t)sn1 * DDIM + d0);
        a0 += bf2f(v0.x); a1 += bf2f(v0.y); a2 += bf2f(v0.z); a3 += bf2f(v0.w);
        b0 += bf2f(v1.x); b1 += bf2f(v1.y); b2 += bf2f(v1.z); b3 += bf2f(v1.w);
    }
    if (j < end) {
        int sn0 = esrc[j];
        ushort4 v0 = *(const ushort4*)(X + (size_t)sn0 * DDIM + d0);
        a0 += bf2f(v0.x); a1 += bf2f(v0.y); a2 += bf2f(v0.z); a3 += bf2f(v0.w);
    }
    a0 += b0; a1 += b1; a2 += b2; a3 += b3;
    float inv = (end > beg) ? 1.0f / (float)(end - beg) : 0.0f;
    float cnt = (end > beg) ? 2.0f : 1.0f;
    ushort4 xv = *(const ushort4*)(X + (size_t)node * DDIM + d0);
    ushort4 o;
    o.x = f2bf(sc[0] * (bf2f(xv.x) + a0 * inv) + tt[0] * cnt);
    o.y = f2bf(sc[1] * (bf2f(xv.y) + a1 * inv) + tt[1] * cnt);
    o.z = f2bf(sc[2] * (bf2f(xv.z) + a2 * inv) + tt[2] * cnt);
    o.w = f2bf(sc[3] * (bf2f(xv.w) + a3 * inv) + tt[3] * cnt);
    *(ushort4*)(Hout + (size_t)node * DDIM + d0) = o;
}

// ---------------- fused MLP: C = relu(relu(A@W1+b1)@W2+b2) + col stats ----------------
// A[MPAD][256] bf16; W1t/W2t[n][k] bf16 pre-transposed; C[MPAD][256] bf16.
// Block: 256 thr = 4 waves (2x2), tile 128 rows x full 256 cols, BK=32.
// Intermediate T (128x256 bf16) lives in LDS, chunk-XOR swizzled (cc ^= row&7).

__global__ __launch_bounds__(256) void k_mlp(const unsigned short* __restrict__ A,
                                             const unsigned short* __restrict__ W1t,
                                             const float* __restrict__ b1,
                                             const unsigned short* __restrict__ W2t,
                                             const float* __restrict__ b2,
                                             unsigned short* __restrict__ C,
                                             float* __restrict__ stat) {
    __shared__ unsigned short Tl[128 * 256];  // 64 KB
    __shared__ unsigned short As[128 * 32];   // 8 KB
    __shared__ unsigned short Bs[128 * 32];   // 8 KB

    const int tid = threadIdx.x;
    const int wv = tid >> 6;
    const int lane = tid & 63;
    const int bm = blockIdx.x;
    const int wr = (wv >> 1) * 64;
    const int wc = (wv & 1) * 64;
    const int lr = lane & 15;
    const int lk = lane >> 4;

    // ---- Phase A: T = relu(A@W1+b1) -> LDS, two column halves ----
    for (int nh = 0; nh < 2; nh++) {
        f32x4 acc[4][4];
#pragma unroll
        for (int m = 0; m < 4; m++)
#pragma unroll
            for (int n = 0; n < 4; n++) acc[m][n] = (f32x4)(0.f);

        for (int k0 = 0; k0 < 256; k0 += 32) {
#pragma unroll
            for (int i = 0; i < 2; i++) {
                int c = wv * 128 + i * 64 + lane;
                int row = c >> 2;
                int kc = (c & 3) ^ ((row >> 1) & 3);
                gld_lds16(A + (size_t)(bm * 128 + row) * 256 + k0 + kc * 8,
                          (void*)&As[(size_t)(wv * 128 + i * 64) * 8]);
                gld_lds16(W1t + (size_t)(nh * 128 + row) * 256 + k0 + kc * 8,
                          (void*)&Bs[(size_t)(wv * 128 + i * 64) * 8]);
            }
            __syncthreads();
            bf16x8 af[4], bfr[4];
#pragma unroll
            for (int m = 0; m < 4; m++) {
                int row = wr + m * 16 + lr;
                af[m] = ((const bf16x8*)As)[row * 4 + (lk ^ ((row >> 1) & 3))];
            }
#pragma unroll
            for (int n = 0; n < 4; n++) {
                int row = wc + n * 16 + lr;
                bfr[n] = ((const bf16x8*)Bs)[row * 4 + (lk ^ ((row >> 1) & 3))];
            }
#pragma unroll
            for (int m = 0; m < 4; m++)
#pragma unroll
                for (int n = 0; n < 4; n++)
                    acc[m][n] = __builtin_amdgcn_mfma_f32_16x16x32_bf16(
                        af[m], bfr[n], acc[m][n], 0, 0, 0);
            __syncthreads();
        }
        // epilogue: relu+bias -> Tl (swizzled scalar writes, ~2-way max)
#pragma unroll
        for (int n = 0; n < 4; n++) {
            int col = nh * 128 + wc + n * 16 + lr;
            float bv = b1[col];
#pragma unroll
            for (int m = 0; m < 4; m++)
#pragma unroll
                for (int i = 0; i < 4; i++) {
                    int row = wr + m * 16 + lk * 4 + i;
                    float v = fmaxf(acc[m][n][i] + bv, 0.f);
                    int cs = (col >> 3) ^ (row & 7);
                    Tl[row * 256 + cs * 8 + (col & 7)] = f2bf(v);
                }
        }
    }
    __syncthreads();  // T complete

    // ---- Phase B: C = relu(T@W2+b2), A-frags straight from Tl ----
    for (int nh = 0; nh < 2; nh++) {
        f32x4 acc[4][4];
#pragma unroll
        for (int m = 0; m < 4; m++)
#pragma unroll
            for (int n = 0; n < 4; n++) acc[m][n] = (f32x4)(0.f);

        for (int k0 = 0; k0 < 256; k0 += 32) {
#pragma unroll
            for (int i = 0; i < 2; i++) {
                int c = wv * 128 + i * 64 + lane;
                int row = c >> 2;
                int kc = (c & 3) ^ ((row >> 1) & 3);
                gld_lds16(W2t + (size_t)(nh * 128 + row) * 256 + k0 + kc * 8,
                          (void*)&Bs[(size_t)(wv * 128 + i * 64) * 8]);
            }
            __syncthreads();
            bf16x8 af[4], bfr[4];
#pragma unroll
            for (int m = 0; m < 4; m++) {
                int row = wr + m * 16 + lr;
                int cs = ((k0 >> 3) + lk) ^ (row & 7);
                af[m] = ((const bf16x8*)Tl)[row * 32 + cs];
            }
#pragma unroll
            for (int n = 0; n < 4; n++) {
                int row = wc + n * 16 + lr;
                bfr[n] = ((const bf16x8*)Bs)[row * 4 + (lk ^ ((row >> 1) & 3))];
            }
#pragma unroll
            for (int m = 0; m < 4; m++)
#pragma unroll
                for (int n = 0; n < 4; n++)
                    acc[m][n] = __builtin_amdgcn_mfma_f32_16x16x32_bf16(
                        af[m], bfr[n], acc[m][n], 0, 0, 0);
            __syncthreads();
        }
        // epilogue: relu+bias -> global C, fused column stats
#pragma unroll
        for (int n = 0; n < 4; n++) {
            int col = nh * 128 + wc + n * 16 + lr;
            float bv = b2[col];
            float sp = 0.f, ssp = 0.f;
#pragma unroll
            for (int m = 0; m < 4; m++)
#pragma unroll
                for (int i = 0; i < 4; i++) {
                    int row = bm * 128 + wr + m * 16 + lk * 4 + i;
                    float v = fmaxf(acc[m][n][i] + bv, 0.f);
                    C[(size_t)row * 256 + col] = f2bf(v);
                    if (row < N_NODESC) { sp += v; ssp += v * v; }
                }
            sp += __shfl_xor(sp, 16);
            sp += __shfl_xor(sp, 32);
            ssp += __shfl_xor(ssp, 16);
            ssp += __shfl_xor(ssp, 32);
            if (lane < 16) {
                atomicAdd(&stat[col], sp);
                atomicAdd(&stat[256 + col], ssp);
            }
        }
    }
}

// ---------------- classification head (applies final BN inline) ----------------

__global__ __launch_bounds__(256) void k_head(const unsigned short* __restrict__ Y,
                                              const int* __restrict__ counts,
                                              const float* __restrict__ stat,
                                              const float* __restrict__ gamma,
                                              const float* __restrict__ beta,
                                              const float* __restrict__ fcW1,
                                              const float* __restrict__ fcb1,
                                              const float* __restrict__ fcW2,
                                              const float* __restrict__ fcb2,
                                              float* __restrict__ out) {
    int g = blockIdx.x;
    __shared__ float row[DDIM];
    __shared__ float gv[DDIM];
    __shared__ float logits[NCLS];
    __shared__ int lastIdx;
    if (threadIdx.x == 0) {
        int s = 0;
        for (int i = 0; i <= g; i++) s += counts[i];
        lastIdx = s - 1;
    }
    __syncthreads();
    int j = threadIdx.x;
    const float invN = 1.0f / (float)N_NODESC;
    float mu = stat[j] * invN;
    float var = stat[256 + j] * invN - mu * mu;
    float sc = gamma[j] * rsqrtf(var + BN_EPSF);
    row[j] = sc * (bf2f(Y[(size_t)lastIdx * DDIM + j]) - mu) + beta[j];
    __syncthreads();
    float acc = fcb1[j];
    for (int d = 0; d < DDIM; d++) acc += row[d] * fcW1[(size_t)d * DDIM + j];
    gv[j] = fmaxf(acc, 0.f);
    __syncthreads();
    if (j < NCLS) {
        float a = fcb2[j];
        for (int d = 0; d < DDIM; d++) a += gv[d] * fcW2[(size_t)d * NCLS + j];
        logits[j] = a;
    }
    __syncthreads();
    if (j == 0) {
        float m = -1e30f;
        for (int c = 0; c < NCLS; c++) m = fmaxf(m, logits[c]);
        float se = 0.f;
        for (int c = 0; c < NCLS; c++) se += expf(logits[c] - m);
        float lse = m + logf(se);
        for (int c = 0; c < NCLS; c++) out[g * NCLS + c] = logits[c] - lse;
    }
}

// ---------------- launcher ----------------

extern "C" void kernel_launch(void* const* d_in, const int* in_sizes, int n_in,
                              void* d_out, int out_size, void* d_ws, size_t ws_size,
                              hipStream_t stream) {
    const float* x    = (const float*)d_in[0];
    const int* src    = (const int*)d_in[1];
    const int* dst    = (const int*)d_in[2];
    const int* counts = (const int*)d_in[3];
    const float* W1a  = (const float*)d_in[4];
    const float* b1a  = (const float*)d_in[5];
    const float* W1b  = (const float*)d_in[6];
    const float* b1b  = (const float*)d_in[7];
    const float* g1   = (const float*)d_in[8];
    const float* be1  = (const float*)d_in[9];
    const float* Ws1  = (const float*)d_in[10];
    const float* bs1  = (const float*)d_in[11];
    const float* Ws2  = (const float*)d_in[12];
    const float* bs2  = (const float*)d_in[13];
    const float* gms  = (const float*)d_in[14];
    const float* bts  = (const float*)d_in[15];
    const float* fcW1 = (const float*)d_in[16];
    const float* fcb1 = (const float*)d_in[17];
    const float* fcW2 = (const float*)d_in[18];
    const float* fcb2 = (const float*)d_in[19];
    float* out = (float*)d_out;

    char* ws = (char*)d_ws;
    const size_t BUF = (size_t)MPAD * DDIM * 2;  // 25,624,576 B
    unsigned short* B0 = (unsigned short*)(ws);
    unsigned short* B1 = (unsigned short*)(ws + BUF);
    unsigned short* Bx = (unsigned short*)(ws + 2 * BUF);
    unsigned short* Wt = (unsigned short*)(ws + 3 * BUF);          // 1,310,720 B
    int* rowstart      = (int*)(ws + 3 * BUF + 1310720);           // 200,064 B
    int* cursor        = (int*)(ws + 3 * BUF + 1510784);           // 200,064 B
    int* esrc          = (int*)(ws + 3 * BUF + 1710848);           // 1,600,000 B
    float* colsum      = (float*)(ws + 3 * BUF + 3310848);         // 2,048 B
    int* bsum          = (int*)(ws + 3 * BUF + 3312896);           // 784 B

    // ---- CSR build ----
    k_zero32<<<dim3((N_NODESC + 255) / 256), 256, 0, stream>>>(cursor, N_NODESC);
    k_count<<<dim3((N_EDGESC + 255) / 256), 256, 0, stream>>>(dst, cursor);
    k_scan1<<<dim3(NBLK_SCAN), 256, 0, stream>>>(cursor, rowstart, bsum);
    k_scan2<<<dim3(NBLK_SCAN), 256, 0, stream>>>(rowstart, bsum);
    k_zero32<<<dim3((N_NODESC + 255) / 256), 256, 0, stream>>>(cursor, N_NODESC);
    k_fill<<<dim3((N_EDGESC + 255) / 256), 256, 0, stream>>>(src, dst, rowstart,
                                                             cursor, esrc);

    // ---- prep: weights, x->bf16, pad zeroing ----
    k_wprep<<<dim3((10 * 65536 + 255) / 256), 256, 0, stream>>>(W1a, W1b, Ws1, Ws2, Wt);
    k_xbf<<<dim3(12500), 256, 0, stream>>>(x, Bx);
    k_zeropad<<<dim3(((MPAD - N_NODESC) * DDIM + 255) / 256), 256, 0, stream>>>(B1);

    // ---- 5 GIN layers (BN of layer l applied inside agg of layer l+1 / head) ----
    for (int l = 0; l < 5; ++l) {
        const float* B1b = (l == 0) ? b1a : bs1 + (l - 1) * 256;
        const float* B2b = (l == 0) ? b1b : bs2 + (l - 1) * 256;
        const unsigned short* Wt1 = Wt + (size_t)(l * 2) * 65536;
        const unsigned short* Wt2 = Wt + (size_t)(l * 2 + 1) * 65536;

        if (l == 0) {
            k_agg_bf<<<dim3(12500), 256, 0, stream>>>(Bx, esrc, rowstart, nullptr,
                                                      nullptr, nullptr, B1);
        } else {
            const float* GA = (l == 1) ? g1 : gms + (l - 2) * 256;
            const float* BE = (l == 1) ? be1 : bts + (l - 2) * 256;
            k_agg_bf<<<dim3(12500), 256, 0, stream>>>(B0, esrc, rowstart, colsum,
                                                      GA, BE, B1);
        }
        k_zero32<<<1, 512, 0, stream>>>((int*)colsum, 512);
        k_mlp<<<dim3(MPAD / 128), 256, 0, stream>>>(B1, Wt1, B1b, Wt2, B2b, B0,
                                                    colsum);
    }

    // ---- head (applies layer-4 BN inline) ----
    k_head<<<dim3(N_GRAPHSC), 256, 0, stream>>>(B0, counts, colsum,
                                                gms + 3 * 256, bts + 3 * 256,
                                                fcW1, fcb1, fcW2, fcb2, out);
}